// Round 1
// baseline (134.711 us; speedup 1.0000x reference)
//
#include <hip/hip_runtime.h>
#include <hip/hip_bf16.h>

#define NN 4096
#define DD 256
#define RPB 64                    // rows per block
#define CPT 64                    // cols per tile
#define COLCHUNKS 4
#define CPW (NN / COLCHUNKS)      // 1024 cols per workgroup
#define TILES (CPW / CPT)         // 16
#define LSTR 264                  // LDS row stride in bf16 units (pad: 264*2B=528B, 132 dwords, 132%32=4)

typedef __attribute__((ext_vector_type(8))) short bf16x8;
typedef __attribute__((ext_vector_type(4))) float f32x4;

#define LOG2E 1.44269504088896f

// ---- kernel 1: L2-normalize rows of z_i, z_j and cast to bf16 ----
__global__ __launch_bounds__(256) void k_norm(const float* __restrict__ zi,
                                              const float* __restrict__ zj,
                                              __hip_bfloat16* __restrict__ oi,
                                              __hip_bfloat16* __restrict__ oj) {
  int gw = (blockIdx.x * 256 + threadIdx.x) >> 6;  // global wave id, one row each
  int lane = threadIdx.x & 63;
  const float* src = (gw < NN) ? zi : zj;
  __hip_bfloat16* dst = (gw < NN) ? oi : oj;
  int row = (gw < NN) ? gw : gw - NN;
  float4 v = ((const float4*)(src + (size_t)row * DD))[lane];
  float ss = v.x * v.x + v.y * v.y + v.z * v.z + v.w * v.w;
#pragma unroll
  for (int m = 1; m < 64; m <<= 1) ss += __shfl_xor(ss, m);
  float s = 1.0f / fmaxf(sqrtf(ss), 1e-12f);
  __hip_bfloat16* d = dst + (size_t)row * DD + lane * 4;
  d[0] = __float2bfloat16(v.x * s);
  d[1] = __float2bfloat16(v.y * s);
  d[2] = __float2bfloat16(v.z * s);
  d[3] = __float2bfloat16(v.w * s);
}

// ---- kernel 2: fused similarity + reduction passes ----
// blockIdx.z selects combo: 0: S_ij=zin·zjn^T  1: S_ji=zjn·zin^T  2: S_ii  3: S_jj
// stats layout: [13][NN] floats: 0..3 = pure exp sums (A1 ij, A2 ii, A3 ji, A4 jj),
//   4..7 = sup exp sums (B1..B4 same order), 8..11 = RBF-weighted sums (C1..C4), 12 = T
__global__ __launch_bounds__(256, 2) void k_main(
    const __hip_bfloat16* __restrict__ zin, const __hip_bfloat16* __restrict__ zjn,
    const float* __restrict__ labels,
    float* __restrict__ stats, float* __restrict__ diag) {
  __shared__ short lA[RPB * LSTR];
  __shared__ short lB[CPT * LSTR];

  const int combo = blockIdx.z;
  const __hip_bfloat16* Ap;
  const __hip_bfloat16* Bp;
  int s0, s1, s2, flags;  // flags: 1 = exclude diagonal, 2 = record diag, 4 = accumulate T
  switch (combo) {
    case 0:  Ap = zin; Bp = zjn; s0 = 0; s1 = 4; s2 = 8;  flags = 2; break;
    case 1:  Ap = zjn; Bp = zin; s0 = 2; s1 = 6; s2 = 10; flags = 0; break;
    case 2:  Ap = zin; Bp = zin; s0 = 1; s1 = 5; s2 = 9;  flags = 5; break;
    default: Ap = zjn; Bp = zjn; s0 = 3; s1 = 7; s2 = 11; flags = 1; break;
  }
  const int rowbase = blockIdx.y * RPB;
  const int colchunk = blockIdx.x;
  const int tid = threadIdx.x;
  const int lane = tid & 63;
  const int wave = tid >> 6;

  // stage A rows once (64 x 256 bf16), coalesced 16B per thread
#pragma unroll
  for (int j = 0; j < 8; ++j) {
    int f8 = tid + 256 * j;
    int r = f8 >> 5, u = f8 & 31;
    bf16x8 v = *(const bf16x8*)(Ap + (size_t)(rowbase + r) * DD + u * 8);
    *(bf16x8*)(lA + r * LSTR + u * 8) = v;
  }

  const int fr = lane & 15;  // frag row (A) / col (B) index
  const int kg = lane >> 4;  // k-group 0..3
  const int koff = kg * 8;

  // epilogue rows for this lane: rowbase + wave*16 + kg*4 + reg  (C/D layout, m89)
  float labr[4];
#pragma unroll
  for (int reg = 0; reg < 4; ++reg)
    labr[reg] = labels[rowbase + wave * 16 + kg * 4 + reg];

  float stA[4] = {0.f, 0.f, 0.f, 0.f};
  float stB[4] = {0.f, 0.f, 0.f, 0.f};
  float stC[4] = {0.f, 0.f, 0.f, 0.f};
  float stT[4] = {0.f, 0.f, 0.f, 0.f};

  for (int t = 0; t < TILES; ++t) {
    const int colbase = colchunk * CPW + t * CPT;
    __syncthreads();  // previous tile's reads (and initial lA writes) complete
#pragma unroll
    for (int j = 0; j < 8; ++j) {
      int f8 = tid + 256 * j;
      int r = f8 >> 5, u = f8 & 31;
      bf16x8 v = *(const bf16x8*)(Bp + (size_t)(colbase + r) * DD + u * 8);
      *(bf16x8*)(lB + r * LSTR + u * 8) = v;
    }
    __syncthreads();

    f32x4 acc[4];
#pragma unroll
    for (int cf = 0; cf < 4; ++cf) acc[cf] = (f32x4){0.f, 0.f, 0.f, 0.f};

#pragma unroll
    for (int k = 0; k < 8; ++k) {
      bf16x8 a = *(const bf16x8*)(lA + (wave * 16 + fr) * LSTR + k * 32 + koff);
#pragma unroll
      for (int cf = 0; cf < 4; ++cf) {
        bf16x8 b = *(const bf16x8*)(lB + (cf * 16 + fr) * LSTR + k * 32 + koff);
        acc[cf] = __builtin_amdgcn_mfma_f32_16x16x32_bf16(a, b, acc[cf], 0, 0, 0);
      }
    }

    // epilogue: convert tile results to per-row stat contributions
#pragma unroll
    for (int cf = 0; cf < 4; ++cf) {
      int cg = colbase + cf * 16 + fr;
      float labc = labels[cg];
#pragma unroll
      for (int reg = 0; reg < 4; ++reg) {
        int rg = rowbase + wave * 16 + kg * 4 + reg;
        float S = acc[cf][reg];
        float dl = labr[reg] - labc;
        float K = exp2f(-(0.5f * LOG2E) * dl * dl);  // exp(-0.5*dl^2), GAMMA=0.5
        stT[reg] += K;                               // includes diagonal (K=1)
        bool isdiag = (rg == cg);
        if (isdiag) {
          if (flags & 2) diag[rg] = S;
          if (flags & 1) continue;  // ii/jj: -INF on diagonal, weight zeroed
        }
        stA[reg] += exp2f((10.f * LOG2E) * S - (10.f * LOG2E));  // exp(S/0.1 - 10)
        stB[reg] += exp2f((2.f * LOG2E) * S - (2.f * LOG2E));    // exp(S/0.5 - 2)
        stC[reg] += K * S;
      }
    }
  }

  // reduce over the 16 columns handled within each 16-lane group, then accumulate
#pragma unroll
  for (int reg = 0; reg < 4; ++reg) {
    float a = stA[reg], b = stB[reg], c = stC[reg], tt = stT[reg];
#pragma unroll
    for (int m = 1; m < 16; m <<= 1) {
      a += __shfl_xor(a, m);
      b += __shfl_xor(b, m);
      c += __shfl_xor(c, m);
      tt += __shfl_xor(tt, m);
    }
    if (fr == 0) {
      int rg = rowbase + wave * 16 + kg * 4 + reg;
      atomicAdd(&stats[s0 * NN + rg], a);
      atomicAdd(&stats[s1 * NN + rg], b);
      atomicAdd(&stats[s2 * NN + rg], c);
      if (flags & 4) atomicAdd(&stats[12 * NN + rg], tt);
    }
  }
}

// ---- kernel 3: finalize scalar loss ----
__global__ __launch_bounds__(256) void k_final(const float* __restrict__ stats,
                                               const float* __restrict__ diag,
                                               float* __restrict__ out) {
  __shared__ float red[2][4];
  float accP = 0.f, accS = 0.f;
  for (int i = threadIdx.x; i < NN; i += 256) {
    float A1 = stats[0 * NN + i], A2 = stats[1 * NN + i];
    float A3 = stats[2 * NN + i], A4 = stats[3 * NN + i];
    float B1 = stats[4 * NN + i], B2 = stats[5 * NN + i];
    float B3 = stats[6 * NN + i], B4 = stats[7 * NN + i];
    float C1 = stats[8 * NN + i], C2 = stats[9 * NN + i];
    float C3 = stats[10 * NN + i], C4 = stats[11 * NN + i];
    float T = stats[12 * NN + i];
    float d = diag[i];
    // loss_i + loss_j: (10 + log(A1+A2) - 10 d) + (10 + log(A3+A4) - 10 d)
    accP += logf(A1 + A2) + logf(A3 + A4) + 20.f - 20.f * d;
    float nrm = 2.f * T - 1.f;
    float W = 2.f * (C1 + C2 + C3 + C4) / nrm;                // sum_b w*sZ (x1/TEMP_SUP)
    float lse = logf(B1 + B2) + logf(B3 + B4) + 4.f;          // lse_top + lse_bot
    accS += lse - W - 2.f * logf(nrm);                        // -(W - lse) - 2 log nrm
  }
#pragma unroll
  for (int m = 1; m < 64; m <<= 1) {
    accP += __shfl_xor(accP, m);
    accS += __shfl_xor(accS, m);
  }
  int wave = threadIdx.x >> 6, lane = threadIdx.x & 63;
  if (lane == 0) { red[0][wave] = accP; red[1][wave] = accS; }
  __syncthreads();
  if (threadIdx.x == 0) {
    float P = red[0][0] + red[0][1] + red[0][2] + red[0][3];
    float Ssum = red[1][0] + red[1][1] + red[1][2] + red[1][3];
    float loss_pure = P / (float)NN;
    float loss_sup = Ssum / (float)NN;
    out[0] = 0.5f * loss_pure + 0.5f * loss_sup;
  }
}

extern "C" void kernel_launch(void* const* d_in, const int* in_sizes, int n_in,
                              void* d_out, int out_size, void* d_ws, size_t ws_size,
                              hipStream_t stream) {
  const float* zi = (const float*)d_in[0];
  const float* zj = (const float*)d_in[1];
  const float* labels = (const float*)d_in[2];
  float* out = (float*)d_out;

  char* ws = (char*)d_ws;
  __hip_bfloat16* zinH = (__hip_bfloat16*)ws;                          // 2 MB
  __hip_bfloat16* zjnH = (__hip_bfloat16*)(ws + (size_t)NN * DD * 2);  // 2 MB
  float* stats = (float*)(ws + (size_t)NN * DD * 4);                   // 13*NN floats
  float* diag = stats + 13 * NN;                                       // NN floats

  hipMemsetAsync(stats, 0, 13 * NN * sizeof(float), stream);

  k_norm<<<2 * NN / 4, 256, 0, stream>>>(zi, zj, zinH, zjnH);

  dim3 grid(COLCHUNKS, NN / RPB, 4);
  k_main<<<grid, 256, 0, stream>>>(zinH, zjnH, labels, stats, diag);

  k_final<<<1, 256, 0, stream>>>(stats, diag, out);
}